// Round 3
// baseline (1700.439 us; speedup 1.0000x reference)
//
#include <hip/hip_runtime.h>
#include <hip/hip_bf16.h>
#include <cstdint>
#include <cstddef>

#define UNITS 1024
#define BDIM 32
#define TDIM 2048
#define M_TOT (BDIM*TDIM)   /* 65536 */
#define KDIM UNITS
#define NDIM UNITS

#define K2LOG2E 2.885390081777927f   /* 2*log2(e): tanh(x) = 1 - 2/(exp2(x*K2LOG2E)+1) */

typedef __attribute__((ext_vector_type(8))) short bf16x8;           // 8 bf16 = 4 VGPRs
typedef __attribute__((ext_vector_type(8))) unsigned short ushort8;
typedef __attribute__((ext_vector_type(4))) float f32x4;

__device__ __forceinline__ unsigned short f2bf(float f) {
  unsigned u = __float_as_uint(f);
  u += 0x7fffu + ((u >> 16) & 1u);          // round-to-nearest-even
  return (unsigned short)(u >> 16);
}
__device__ __forceinline__ float bf2f(unsigned short h) {
  return __uint_as_float(((unsigned)h) << 16);
}

// ---------------- fp32 -> bf16 conversion (8 floats / thread / iter) --------
__global__ __launch_bounds__(256) void cvt_kernel(const float* __restrict__ src,
                                                  ushort* __restrict__ dst, int n8) {
  int i = blockIdx.x * blockDim.x + threadIdx.x;
  int stride = gridDim.x * blockDim.x;
  const float4* s4 = (const float4*)src;
  ushort8* d8 = (ushort8*)dst;
  for (; i < n8; i += stride) {
    float4 a = s4[2*i], b = s4[2*i+1];
    ushort8 o;
    o[0] = f2bf(a.x); o[1] = f2bf(a.y); o[2] = f2bf(a.z); o[3] = f2bf(a.w);
    o[4] = f2bf(b.x); o[5] = f2bf(b.y); o[6] = f2bf(b.z); o[7] = f2bf(b.w);
    d8[i] = o;                                   // one 16B store
  }
}

// ---------------- c[b,v] = W1_b[v] + W2_b[v] + dot(W2[v,:], hidden[b,:]) ----
__global__ __launch_bounds__(64) void prep_c_kernel(const float* __restrict__ W2w,
                                                    const float* __restrict__ hidden,
                                                    const float* __restrict__ W1b,
                                                    const float* __restrict__ W2b,
                                                    float* __restrict__ c) {
  int v = blockIdx.x;
  int l = threadIdx.x;
  float acc[BDIM];
  #pragma unroll
  for (int b = 0; b < BDIM; b++) acc[b] = 0.f;
  for (int u0 = 0; u0 < UNITS; u0 += 64) {
    float w = W2w[v*UNITS + u0 + l];           // coalesced over lanes
    #pragma unroll
    for (int b = 0; b < BDIM; b++) acc[b] += w * hidden[b*UNITS + u0 + l];
  }
  float bias = W1b[v] + W2b[v];
  #pragma unroll
  for (int b = 0; b < BDIM; b++) {
    float s = acc[b];
    #pragma unroll
    for (int off = 32; off > 0; off >>= 1) s += __shfl_xor(s, off);
    if (l == 0) c[b*UNITS + v] = s + bias;
  }
}

// ---------------- fused GEMM + tanh + V-dot -> partial scores ---------------
// Block = 128 m-rows x half of N (2 passes of 256 n). Grid (512 m, 2 halves)
// = 1024 blocks = 4 blocks/CU (occupancy play). Partial score per half,
// summed exactly in softmax — no atomics.
__global__ __launch_bounds__(256, 4) void gemm_score_kernel(
    const ushort* __restrict__ A,   // M x K bf16 (row-major)
    const ushort* __restrict__ W,   // N x K bf16 (row-major)
    const float* __restrict__ c,    // B x N
    const float* __restrict__ Vw,   // N
    float* __restrict__ score)      // 2 x M partials (written exactly once)
{
  __shared__ ushort As[128*32];   // 8 KB
  __shared__ ushort Bs[256*32];   // 16 KB
  __shared__ float sred[256];     // cross-wave score reduction

  const int m0 = blockIdx.x * 128;
  const int half = blockIdx.y;              // n-half: 0 or 1
  const int bb = m0 >> 11;                  // 128 rows share one b (T=2048)
  const int tid = threadIdx.x;
  const int wave = tid >> 6;
  const int l = tid & 63;
  const int lrow = l & 15;                  // n within 16x16 frag
  const int lq = l >> 4;                    // m quad
  const int wm = (wave >> 1) * 64;          // wave m-offset (0 / 64)
  const int wn = (wave & 1) * 128;          // wave n-offset (0 / 128)

  // staging: lane -> (row = tid>>2, 16B col slot = tid&3), swizzled column
  const int srow = tid >> 2;                              // 0..63
  const int scol = ((tid & 3) - (tid >> 3)) & 3;          // rotation swizzle (R2: 0 conflicts)
  const int skc  = scol * 8;
  // fragment read slot (inverse swizzle)
  const int slot = (lq + (lrow >> 1)) & 3;
  const int aoff = (wm + lrow) * 32 + slot * 8;
  const int boff = (wn + lrow) * 32 + slot * 8;

  // wave-uniform LDS staging bases (HW scatters lane*16B)
  ushort* lA0 = As + wave * 512;
  ushort* lA1 = As + 2048 + wave * 512;
  ushort* lB0 = Bs + wave * 512;
  ushort* lB1 = Bs + 2048 + wave * 512;
  ushort* lB2 = Bs + 4096 + wave * 512;
  ushort* lB3 = Bs + 6144 + wave * 512;

  float sacc[4][4];
  #pragma unroll
  for (int i = 0; i < 4; i++)
    #pragma unroll
    for (int r = 0; r < 4; r++) sacc[i][r] = 0.f;
  float vws = 0.f;

  for (int np = 0; np < 2; np++) {
    const int n0p = half * 512 + np * 256;
    const ushort* ag0 = A + (size_t)(m0 + srow) * KDIM + skc;
    const ushort* ag1 = ag0 + (size_t)64 * KDIM;
    const ushort* wg0 = W + (size_t)(n0p + srow) * KDIM + skc;
    const ushort* wg1 = wg0 + (size_t)64 * KDIM;
    const ushort* wg2 = wg0 + (size_t)128 * KDIM;
    const ushort* wg3 = wg0 + (size_t)192 * KDIM;

    f32x4 acc[4][8];
    #pragma unroll
    for (int i = 0; i < 4; i++)
      #pragma unroll
      for (int j = 0; j < 8; j++) acc[i][j] = (f32x4)0.f;

    for (int k0 = 0; k0 < KDIM; k0 += 32) {
      __builtin_amdgcn_global_load_lds((const __attribute__((address_space(1))) void*)ag0,
                                       (__attribute__((address_space(3))) void*)lA0, 16, 0, 0);
      __builtin_amdgcn_global_load_lds((const __attribute__((address_space(1))) void*)ag1,
                                       (__attribute__((address_space(3))) void*)lA1, 16, 0, 0);
      __builtin_amdgcn_global_load_lds((const __attribute__((address_space(1))) void*)wg0,
                                       (__attribute__((address_space(3))) void*)lB0, 16, 0, 0);
      __builtin_amdgcn_global_load_lds((const __attribute__((address_space(1))) void*)wg1,
                                       (__attribute__((address_space(3))) void*)lB1, 16, 0, 0);
      __builtin_amdgcn_global_load_lds((const __attribute__((address_space(1))) void*)wg2,
                                       (__attribute__((address_space(3))) void*)lB2, 16, 0, 0);
      __builtin_amdgcn_global_load_lds((const __attribute__((address_space(1))) void*)wg3,
                                       (__attribute__((address_space(3))) void*)lB3, 16, 0, 0);
      ag0 += 32; ag1 += 32; wg0 += 32; wg1 += 32; wg2 += 32; wg3 += 32;
      __syncthreads();
      bf16x8 af[4], bfv[8];
      #pragma unroll
      for (int i = 0; i < 4; i++) af[i] = *(const bf16x8*)(As + aoff + i * 512);
      #pragma unroll
      for (int j = 0; j < 8; j++) bfv[j] = *(const bf16x8*)(Bs + boff + j * 512);
      #pragma unroll
      for (int i = 0; i < 4; i++)
        #pragma unroll
        for (int j = 0; j < 8; j++)
          acc[i][j] = __builtin_amdgcn_mfma_f32_16x16x32_bf16(af[i], bfv[j], acc[i][j], 0, 0, 0);
      __syncthreads();
    }

    // epilogue: sacc += vw * sigmoid-ish; partial score = vws - 2*sacc
    float vw8[8], ck8[8];
    #pragma unroll
    for (int j = 0; j < 8; j++) {
      int n = n0p + wn + j * 16 + lrow;
      float v = Vw[n];
      vw8[j] = v;
      vws += v;
      ck8[j] = c[bb * NDIM + n] * K2LOG2E;
    }
    #pragma unroll
    for (int i = 0; i < 4; i++)
      #pragma unroll
      for (int j = 0; j < 8; j++)
        #pragma unroll
        for (int r = 0; r < 4; r++) {
          float t = __builtin_fmaf(acc[i][j][r], K2LOG2E, ck8[j]);
          float e = __builtin_amdgcn_exp2f(t);        // inf->rcp 0 (tanh=1); 0 (tanh=-1)
          float rr = __builtin_amdgcn_rcpf(e + 1.f);
          sacc[i][r] = __builtin_fmaf(vw8[j], rr, sacc[i][r]);
        }
  }

  // reduce over the 16 n-lanes of each quad, then across the 2 n-waves via LDS
  #pragma unroll
  for (int i = 0; i < 4; i++)
    #pragma unroll
    for (int r = 0; r < 4; r++) {
      float s = vws - 2.f * sacc[i][r];
      s += __shfl_xor(s, 1);
      s += __shfl_xor(s, 2);
      s += __shfl_xor(s, 4);
      s += __shfl_xor(s, 8);
      if (lrow == 0) sred[wave * 64 + i * 16 + lq * 4 + r] = s;
    }
  __syncthreads();
  if (tid < 128) {
    int hh = tid >> 6;            // 0: waves 0+1 (m 0..63), 1: waves 2+3 (m 64..127)
    int ml = tid & 63;
    float v = sred[hh * 128 + ml] + sred[hh * 128 + 64 + ml];
    score[(size_t)half * M_TOT + m0 + tid] = v;
  }
}

// ---------------- softmax over T per b; sums the 2 partial-score halves -----
__global__ __launch_bounds__(256) void softmax_kernel(float* __restrict__ sc,
                                                      float* __restrict__ wout) {
  const int b = blockIdx.x;
  const int tid = threadIdx.x;
  float4* s4 = (float4*)(sc + (size_t)b * TDIM);
  const float4* p4 = (const float4*)(sc + (size_t)M_TOT + (size_t)b * TDIM);
  float4 v0 = s4[2*tid], v1 = s4[2*tid+1];
  float4 u0 = p4[2*tid], u1 = p4[2*tid+1];
  v0.x += u0.x; v0.y += u0.y; v0.z += u0.z; v0.w += u0.w;
  v1.x += u1.x; v1.y += u1.y; v1.z += u1.z; v1.w += u1.w;
  float mx = fmaxf(fmaxf(fmaxf(v0.x,v0.y),fmaxf(v0.z,v0.w)),
                   fmaxf(fmaxf(v1.x,v1.y),fmaxf(v1.z,v1.w)));
  #pragma unroll
  for (int off = 32; off > 0; off >>= 1) mx = fmaxf(mx, __shfl_xor(mx, off));
  __shared__ float redm[4];
  __shared__ float reds[4];
  if ((tid & 63) == 0) redm[tid >> 6] = mx;
  __syncthreads();
  mx = fmaxf(fmaxf(redm[0], redm[1]), fmaxf(redm[2], redm[3]));
  v0.x = __expf(v0.x - mx); v0.y = __expf(v0.y - mx);
  v0.z = __expf(v0.z - mx); v0.w = __expf(v0.w - mx);
  v1.x = __expf(v1.x - mx); v1.y = __expf(v1.y - mx);
  v1.z = __expf(v1.z - mx); v1.w = __expf(v1.w - mx);
  float sum = v0.x+v0.y+v0.z+v0.w+v1.x+v1.y+v1.z+v1.w;
  #pragma unroll
  for (int off = 32; off > 0; off >>= 1) sum += __shfl_xor(sum, off);
  if ((tid & 63) == 0) reds[tid >> 6] = sum;
  __syncthreads();
  sum = reds[0]+reds[1]+reds[2]+reds[3];
  float inv = 1.f / sum;
  v0.x *= inv; v0.y *= inv; v0.z *= inv; v0.w *= inv;
  v1.x *= inv; v1.y *= inv; v1.z *= inv; v1.w *= inv;
  s4[2*tid] = v0; s4[2*tid+1] = v1;                 // ws copy for context pass
  float4* w4 = (float4*)(wout + (size_t)b * TDIM);  // d_out weights
  w4[2*tid] = v0; w4[2*tid+1] = v1;
}

// ---------------- context[b,u] = sum_t w[b,t]*x[b,t,u]  (exact, no atomics) -
// grid (8 u-chunks of 128, 32 b); 256 threads = 16 u-threads x 16 t-rows
__global__ __launch_bounds__(256) void context_kernel(const ushort* __restrict__ xb,
                                                      const float* __restrict__ wgt,
                                                      float* __restrict__ ctx) {
  const int uc = blockIdx.x;
  const int b = blockIdx.y;
  const int tid = threadIdx.x;
  __shared__ float wl[TDIM];
  {
    const float4* wsrc = (const float4*)(wgt + (size_t)b * TDIM);
    float4* wdst = (float4*)wl;
    wdst[tid] = wsrc[tid];
    wdst[tid + 256] = wsrc[tid + 256];
  }
  __syncthreads();
  const int ut = tid & 15;         // 16 threads x ushort8 = 128 u
  const int tr = tid >> 4;         // 16 t-rows per sweep
  const ushort* xp = xb + (size_t)b * TDIM * UNITS + uc * 128 + ut * 8;
  float a8[8];
  #pragma unroll
  for (int e = 0; e < 8; e++) a8[e] = 0.f;
  for (int t = tr; t < TDIM; t += 64) {            // 4-way unrolled over stride 16
    ushort8 x0 = *(const ushort8*)(xp + (size_t)(t     ) * UNITS);
    ushort8 x1 = *(const ushort8*)(xp + (size_t)(t + 16) * UNITS);
    ushort8 x2 = *(const ushort8*)(xp + (size_t)(t + 32) * UNITS);
    ushort8 x3 = *(const ushort8*)(xp + (size_t)(t + 48) * UNITS);
    float w0 = wl[t], w1 = wl[t+16], w2 = wl[t+32], w3 = wl[t+48];
    #pragma unroll
    for (int e = 0; e < 8; e++) {
      a8[e] += w0 * bf2f(x0[e]);
      a8[e] += w1 * bf2f(x1[e]);
      a8[e] += w2 * bf2f(x2[e]);
      a8[e] += w3 * bf2f(x3[e]);
    }
  }
  // reduce over the 4 t-rows within each wave
  #pragma unroll
  for (int e = 0; e < 8; e++) {
    a8[e] += __shfl_xor(a8[e], 16);
    a8[e] += __shfl_xor(a8[e], 32);
  }
  __shared__ float red[512];
  const int wave = tid >> 6;
  const int l = tid & 63;
  if (l < 16) {
    #pragma unroll
    for (int e = 0; e < 8; e++) red[wave * 128 + l * 8 + e] = a8[e];
  }
  __syncthreads();
  if (tid < 128) {
    float v = red[tid] + red[128 + tid] + red[256 + tid] + red[384 + tid];
    ctx[(size_t)b * UNITS + uc * 128 + tid] = v;
  }
}

extern "C" void kernel_launch(void* const* d_in, const int* in_sizes, int n_in,
                              void* d_out, int out_size, void* d_ws, size_t ws_size,
                              hipStream_t stream) {
  const float* x   = (const float*)d_in[0];
  const float* hid = (const float*)d_in[1];
  const float* W1w = (const float*)d_in[2];
  const float* W1b = (const float*)d_in[3];
  const float* W2w = (const float*)d_in[4];
  const float* W2b = (const float*)d_in[5];
  const float* Vw  = (const float*)d_in[6];
  // d_in[7] (V_b) intentionally unused: softmax is shift-invariant.
  float* out = (float*)d_out;

  char* ws = (char*)d_ws;
  ushort* xb   = (ushort*)ws;                                        // 128 MB
  ushort* w1b  = (ushort*)(ws + (size_t)M_TOT*KDIM*2);               // 2 MB
  float*  cbuf = (float*)(ws + (size_t)M_TOT*KDIM*2 + (size_t)NDIM*KDIM*2); // 128 KB
  float*  score= (float*)((char*)cbuf + (size_t)BDIM*NDIM*4);        // 2 x 256 KB partials

  cvt_kernel<<<4096, 256, 0, stream>>>(x, xb, M_TOT*KDIM/8);
  cvt_kernel<<<512, 256, 0, stream>>>(W1w, w1b, NDIM*KDIM/8);
  prep_c_kernel<<<NDIM, 64, 0, stream>>>(W2w, hid, W1b, W2b, cbuf);
  gemm_score_kernel<<<dim3(M_TOT/128, 2), 256, 0, stream>>>(xb, w1b, cbuf, Vw, score);
  softmax_kernel<<<BDIM, 256, 0, stream>>>(score, out + (size_t)BDIM*UNITS);
  context_kernel<<<dim3(8, BDIM), 256, 0, stream>>>(xb, score, out);
}

// Round 4
// 578.135 us; speedup vs baseline: 2.9412x; 2.9412x over previous
//
#include <hip/hip_runtime.h>
#include <hip/hip_bf16.h>
#include <cstdint>
#include <cstddef>

#define UNITS 1024
#define BDIM 32
#define TDIM 2048
#define M_TOT (BDIM*TDIM)   /* 65536 */
#define KDIM UNITS
#define NDIM UNITS
#define NPART 8              /* score partials = n-tiles of 128 */

#define K2LOG2E 2.885390081777927f   /* 2*log2(e): tanh(x) = 1 - 2/(exp2(x*K2LOG2E)+1) */

typedef __attribute__((ext_vector_type(8))) short bf16x8;           // 8 bf16 = 4 VGPRs
typedef __attribute__((ext_vector_type(8))) unsigned short ushort8;
typedef __attribute__((ext_vector_type(4))) float f32x4;

__device__ __forceinline__ unsigned short f2bf(float f) {
  unsigned u = __float_as_uint(f);
  u += 0x7fffu + ((u >> 16) & 1u);          // round-to-nearest-even
  return (unsigned short)(u >> 16);
}
__device__ __forceinline__ float bf2f(unsigned short h) {
  return __uint_as_float(((unsigned)h) << 16);
}

// ---------------- fp32 -> bf16 conversion (8 floats / thread / iter) --------
__global__ __launch_bounds__(256) void cvt_kernel(const float* __restrict__ src,
                                                  ushort* __restrict__ dst, int n8) {
  int i = blockIdx.x * blockDim.x + threadIdx.x;
  int stride = gridDim.x * blockDim.x;
  const float4* s4 = (const float4*)src;
  ushort8* d8 = (ushort8*)dst;
  for (; i < n8; i += stride) {
    float4 a = s4[2*i], b = s4[2*i+1];
    ushort8 o;
    o[0] = f2bf(a.x); o[1] = f2bf(a.y); o[2] = f2bf(a.z); o[3] = f2bf(a.w);
    o[4] = f2bf(b.x); o[5] = f2bf(b.y); o[6] = f2bf(b.z); o[7] = f2bf(b.w);
    d8[i] = o;                                   // one 16B store
  }
}

// ---------------- c[b,v] = W1_b[v] + W2_b[v] + dot(W2[v,:], hidden[b,:]) ----
__global__ __launch_bounds__(64) void prep_c_kernel(const float* __restrict__ W2w,
                                                    const float* __restrict__ hidden,
                                                    const float* __restrict__ W1b,
                                                    const float* __restrict__ W2b,
                                                    float* __restrict__ c) {
  int v = blockIdx.x;
  int l = threadIdx.x;
  float acc[BDIM];
  #pragma unroll
  for (int b = 0; b < BDIM; b++) acc[b] = 0.f;
  for (int u0 = 0; u0 < UNITS; u0 += 64) {
    float w = W2w[v*UNITS + u0 + l];           // coalesced over lanes
    #pragma unroll
    for (int b = 0; b < BDIM; b++) acc[b] += w * hidden[b*UNITS + u0 + l];
  }
  float bias = W1b[v] + W2b[v];
  #pragma unroll
  for (int b = 0; b < BDIM; b++) {
    float s = acc[b];
    #pragma unroll
    for (int off = 32; off > 0; off >>= 1) s += __shfl_xor(s, off);
    if (l == 0) c[b*UNITS + v] = s + bias;
  }
}

// ---------------- fused GEMM + tanh + V-dot -> partial scores ---------------
// One 128m x 128n tile per block, BK=64 (32 MFMA per barrier-pair per wave).
// Waves 2x2 of 64x64 (acc[4][4] = 64 regs -> fits 3 blocks/CU at (256,3)).
// Grid 4096 = 512 m-tiles x 8 n-tiles (nt-minor: XCD L2 pins one B n-tile).
// Each n-tile writes its own exact score partial; softmax sums the 8.
__global__ __launch_bounds__(256, 3) void gemm_score_kernel(
    const ushort* __restrict__ A,   // M x K bf16 (row-major)
    const ushort* __restrict__ W,   // N x K bf16 (row-major)
    const float* __restrict__ c,    // B x N
    const float* __restrict__ Vw,   // N
    float* __restrict__ score)      // NPART x M partials (each written once)
{
  __shared__ ushort As[128*64];   // 16 KB
  __shared__ ushort Bs[128*64];   // 16 KB
  __shared__ float sred[256];     // cross-wave score reduction

  const int nt = blockIdx.x & 7;            // n-tile 0..7
  const int m0 = (blockIdx.x >> 3) * 128;
  const int n0 = nt * 128;
  const int bb = m0 >> 11;                  // 128 rows share one b (T=2048)
  const int tid = threadIdx.x;
  const int wave = tid >> 6;
  const int l = tid & 63;
  const int lrow = l & 15;                  // n within 16x16 frag
  const int lq = l >> 4;                    // quad
  const int wm = (wave >> 1) * 64;          // wave m-offset (0 / 64)
  const int wn = (wave & 1) * 64;           // wave n-offset (0 / 64)

  // staging: thread -> (row = g*32 + (tid>>3), phys slot = tid&7); content
  // global k-slot s = (phys - row) & 7  (8-slot rotation swizzle)
  const int srow = tid >> 3;                              // 0..31
  const int s_g  = ((tid & 7) - srow) & 7;                // global slot staged
  // fragment read: phys p = (ks*4 + lq + lrow) & 7 (row mod 8 == lrow mod 8)
  const int p0 = ((lq + lrow) & 7) * 8;                   // ksub 0, ushort offset
  const int p1 = (((4 + lq + lrow) & 7)) * 8;             // ksub 1
  const int abase = (wm + lrow) * 64;
  const int bbase = (wn + lrow) * 64;

  // global staging pointers (advance 64 elems per K-iter)
  const ushort* ag0 = A + (size_t)(m0 + srow) * KDIM + s_g * 8;
  const ushort* ag1 = ag0 + (size_t)32 * KDIM;
  const ushort* ag2 = ag0 + (size_t)64 * KDIM;
  const ushort* ag3 = ag0 + (size_t)96 * KDIM;
  const ushort* bg0 = W + (size_t)(n0 + srow) * KDIM + s_g * 8;
  const ushort* bg1 = bg0 + (size_t)32 * KDIM;
  const ushort* bg2 = bg0 + (size_t)64 * KDIM;
  const ushort* bg3 = bg0 + (size_t)96 * KDIM;

  // wave-uniform LDS staging bases (HW scatters lane*16B)
  ushort* lA0 = As + wave * 512;
  ushort* lA1 = As + 2048 + wave * 512;
  ushort* lA2 = As + 4096 + wave * 512;
  ushort* lA3 = As + 6144 + wave * 512;
  ushort* lB0 = Bs + wave * 512;
  ushort* lB1 = Bs + 2048 + wave * 512;
  ushort* lB2 = Bs + 4096 + wave * 512;
  ushort* lB3 = Bs + 6144 + wave * 512;

  f32x4 acc[4][4];
  #pragma unroll
  for (int i = 0; i < 4; i++)
    #pragma unroll
    for (int j = 0; j < 4; j++) acc[i][j] = (f32x4)0.f;

  for (int k0 = 0; k0 < KDIM; k0 += 64) {
    __builtin_amdgcn_global_load_lds((const __attribute__((address_space(1))) void*)ag0,
                                     (__attribute__((address_space(3))) void*)lA0, 16, 0, 0);
    __builtin_amdgcn_global_load_lds((const __attribute__((address_space(1))) void*)ag1,
                                     (__attribute__((address_space(3))) void*)lA1, 16, 0, 0);
    __builtin_amdgcn_global_load_lds((const __attribute__((address_space(1))) void*)ag2,
                                     (__attribute__((address_space(3))) void*)lA2, 16, 0, 0);
    __builtin_amdgcn_global_load_lds((const __attribute__((address_space(1))) void*)ag3,
                                     (__attribute__((address_space(3))) void*)lA3, 16, 0, 0);
    __builtin_amdgcn_global_load_lds((const __attribute__((address_space(1))) void*)bg0,
                                     (__attribute__((address_space(3))) void*)lB0, 16, 0, 0);
    __builtin_amdgcn_global_load_lds((const __attribute__((address_space(1))) void*)bg1,
                                     (__attribute__((address_space(3))) void*)lB1, 16, 0, 0);
    __builtin_amdgcn_global_load_lds((const __attribute__((address_space(1))) void*)bg2,
                                     (__attribute__((address_space(3))) void*)lB2, 16, 0, 0);
    __builtin_amdgcn_global_load_lds((const __attribute__((address_space(1))) void*)bg3,
                                     (__attribute__((address_space(3))) void*)lB3, 16, 0, 0);
    ag0 += 64; ag1 += 64; ag2 += 64; ag3 += 64;
    bg0 += 64; bg1 += 64; bg2 += 64; bg3 += 64;
    __syncthreads();
    {
      bf16x8 af[4], bfv[4];
      #pragma unroll
      for (int i = 0; i < 4; i++) af[i] = *(const bf16x8*)(As + abase + i * 1024 + p0);
      #pragma unroll
      for (int j = 0; j < 4; j++) bfv[j] = *(const bf16x8*)(Bs + bbase + j * 1024 + p0);
      #pragma unroll
      for (int i = 0; i < 4; i++)
        #pragma unroll
        for (int j = 0; j < 4; j++)
          acc[i][j] = __builtin_amdgcn_mfma_f32_16x16x32_bf16(af[i], bfv[j], acc[i][j], 0, 0, 0);
    }
    {
      bf16x8 af[4], bfv[4];
      #pragma unroll
      for (int i = 0; i < 4; i++) af[i] = *(const bf16x8*)(As + abase + i * 1024 + p1);
      #pragma unroll
      for (int j = 0; j < 4; j++) bfv[j] = *(const bf16x8*)(Bs + bbase + j * 1024 + p1);
      #pragma unroll
      for (int i = 0; i < 4; i++)
        #pragma unroll
        for (int j = 0; j < 4; j++)
          acc[i][j] = __builtin_amdgcn_mfma_f32_16x16x32_bf16(af[i], bfv[j], acc[i][j], 0, 0, 0);
    }
    __syncthreads();
  }

  // epilogue: score_partial = sum_n vw * tanh(C + c) = vws - 2 * sum vw*sigma
  float vw4[4], ck4[4];
  float vws = 0.f;
  #pragma unroll
  for (int j = 0; j < 4; j++) {
    int n = n0 + wn + j * 16 + lrow;
    float v = Vw[n];
    vw4[j] = v;
    vws += v;
    ck4[j] = c[bb * NDIM + n] * K2LOG2E;
  }
  float sacc[4][4];
  #pragma unroll
  for (int i = 0; i < 4; i++)
    #pragma unroll
    for (int r = 0; r < 4; r++) sacc[i][r] = 0.f;
  #pragma unroll
  for (int i = 0; i < 4; i++)
    #pragma unroll
    for (int j = 0; j < 4; j++)
      #pragma unroll
      for (int r = 0; r < 4; r++) {
        float t = __builtin_fmaf(acc[i][j][r], K2LOG2E, ck4[j]);
        float e = __builtin_amdgcn_exp2f(t);        // inf->rcp 0 (tanh=1); 0 (tanh=-1)
        float rr = __builtin_amdgcn_rcpf(e + 1.f);
        sacc[i][r] = __builtin_fmaf(vw4[j], rr, sacc[i][r]);
      }

  // reduce over the 16 n-lanes of each quad, then across the 2 n-waves via LDS
  #pragma unroll
  for (int i = 0; i < 4; i++)
    #pragma unroll
    for (int r = 0; r < 4; r++) {
      float s = vws - 2.f * sacc[i][r];
      s += __shfl_xor(s, 1);
      s += __shfl_xor(s, 2);
      s += __shfl_xor(s, 4);
      s += __shfl_xor(s, 8);
      if (lrow == 0) sred[wave * 64 + i * 16 + lq * 4 + r] = s;
    }
  __syncthreads();
  if (tid < 128) {
    int hh = tid >> 6;            // 0: waves 0+1 (m 0..63), 1: waves 2+3 (m 64..127)
    int ml = tid & 63;
    float v = sred[hh * 128 + ml] + sred[hh * 128 + 64 + ml];
    score[(size_t)nt * M_TOT + m0 + tid] = v;
  }
}

// ---------------- softmax over T per b; sums the NPART partial halves ------
__global__ __launch_bounds__(256) void softmax_kernel(float* __restrict__ sc,
                                                      float* __restrict__ wout) {
  const int b = blockIdx.x;
  const int tid = threadIdx.x;
  float4* s4 = (float4*)(sc + (size_t)b * TDIM);
  float4 v0 = s4[2*tid], v1 = s4[2*tid+1];
  #pragma unroll
  for (int k = 1; k < NPART; k++) {
    const float4* p4 = (const float4*)(sc + (size_t)k * M_TOT + (size_t)b * TDIM);
    float4 u0 = p4[2*tid], u1 = p4[2*tid+1];
    v0.x += u0.x; v0.y += u0.y; v0.z += u0.z; v0.w += u0.w;
    v1.x += u1.x; v1.y += u1.y; v1.z += u1.z; v1.w += u1.w;
  }
  float mx = fmaxf(fmaxf(fmaxf(v0.x,v0.y),fmaxf(v0.z,v0.w)),
                   fmaxf(fmaxf(v1.x,v1.y),fmaxf(v1.z,v1.w)));
  #pragma unroll
  for (int off = 32; off > 0; off >>= 1) mx = fmaxf(mx, __shfl_xor(mx, off));
  __shared__ float redm[4];
  __shared__ float reds[4];
  if ((tid & 63) == 0) redm[tid >> 6] = mx;
  __syncthreads();
  mx = fmaxf(fmaxf(redm[0], redm[1]), fmaxf(redm[2], redm[3]));
  v0.x = __expf(v0.x - mx); v0.y = __expf(v0.y - mx);
  v0.z = __expf(v0.z - mx); v0.w = __expf(v0.w - mx);
  v1.x = __expf(v1.x - mx); v1.y = __expf(v1.y - mx);
  v1.z = __expf(v1.z - mx); v1.w = __expf(v1.w - mx);
  float sum = v0.x+v0.y+v0.z+v0.w+v1.x+v1.y+v1.z+v1.w;
  #pragma unroll
  for (int off = 32; off > 0; off >>= 1) sum += __shfl_xor(sum, off);
  if ((tid & 63) == 0) reds[tid >> 6] = sum;
  __syncthreads();
  sum = reds[0]+reds[1]+reds[2]+reds[3];
  float inv = 1.f / sum;
  v0.x *= inv; v0.y *= inv; v0.z *= inv; v0.w *= inv;
  v1.x *= inv; v1.y *= inv; v1.z *= inv; v1.w *= inv;
  s4[2*tid] = v0; s4[2*tid+1] = v1;                 // ws copy for context pass
  float4* w4 = (float4*)(wout + (size_t)b * TDIM);  // d_out weights
  w4[2*tid] = v0; w4[2*tid+1] = v1;
}

// ---------------- context[b,u] = sum_t w[b,t]*x[b,t,u]  (exact, no atomics) -
// grid (8 u-chunks of 128, 32 b); 256 threads = 16 u-threads x 16 t-rows
__global__ __launch_bounds__(256) void context_kernel(const ushort* __restrict__ xb,
                                                      const float* __restrict__ wgt,
                                                      float* __restrict__ ctx) {
  const int uc = blockIdx.x;
  const int b = blockIdx.y;
  const int tid = threadIdx.x;
  __shared__ float wl[TDIM];
  {
    const float4* wsrc = (const float4*)(wgt + (size_t)b * TDIM);
    float4* wdst = (float4*)wl;
    wdst[tid] = wsrc[tid];
    wdst[tid + 256] = wsrc[tid + 256];
  }
  __syncthreads();
  const int ut = tid & 15;         // 16 threads x ushort8 = 128 u
  const int tr = tid >> 4;         // 16 t-rows per sweep
  const ushort* xp = xb + (size_t)b * TDIM * UNITS + uc * 128 + ut * 8;
  float a8[8];
  #pragma unroll
  for (int e = 0; e < 8; e++) a8[e] = 0.f;
  for (int t = tr; t < TDIM; t += 64) {            // 4-way unrolled over stride 16
    ushort8 x0 = *(const ushort8*)(xp + (size_t)(t     ) * UNITS);
    ushort8 x1 = *(const ushort8*)(xp + (size_t)(t + 16) * UNITS);
    ushort8 x2 = *(const ushort8*)(xp + (size_t)(t + 32) * UNITS);
    ushort8 x3 = *(const ushort8*)(xp + (size_t)(t + 48) * UNITS);
    float w0 = wl[t], w1 = wl[t+16], w2 = wl[t+32], w3 = wl[t+48];
    #pragma unroll
    for (int e = 0; e < 8; e++) {
      a8[e] += w0 * bf2f(x0[e]);
      a8[e] += w1 * bf2f(x1[e]);
      a8[e] += w2 * bf2f(x2[e]);
      a8[e] += w3 * bf2f(x3[e]);
    }
  }
  // reduce over the 4 t-rows within each wave
  #pragma unroll
  for (int e = 0; e < 8; e++) {
    a8[e] += __shfl_xor(a8[e], 16);
    a8[e] += __shfl_xor(a8[e], 32);
  }
  __shared__ float red[512];
  const int wave = tid >> 6;
  const int l = tid & 63;
  if (l < 16) {
    #pragma unroll
    for (int e = 0; e < 8; e++) red[wave * 128 + l * 8 + e] = a8[e];
  }
  __syncthreads();
  if (tid < 128) {
    float v = red[tid] + red[128 + tid] + red[256 + tid] + red[384 + tid];
    ctx[(size_t)b * UNITS + uc * 128 + tid] = v;
  }
}

extern "C" void kernel_launch(void* const* d_in, const int* in_sizes, int n_in,
                              void* d_out, int out_size, void* d_ws, size_t ws_size,
                              hipStream_t stream) {
  const float* x   = (const float*)d_in[0];
  const float* hid = (const float*)d_in[1];
  const float* W1w = (const float*)d_in[2];
  const float* W1b = (const float*)d_in[3];
  const float* W2w = (const float*)d_in[4];
  const float* W2b = (const float*)d_in[5];
  const float* Vw  = (const float*)d_in[6];
  // d_in[7] (V_b) intentionally unused: softmax is shift-invariant.
  float* out = (float*)d_out;

  char* ws = (char*)d_ws;
  ushort* xb   = (ushort*)ws;                                        // 128 MB
  ushort* w1b  = (ushort*)(ws + (size_t)M_TOT*KDIM*2);               // 2 MB
  float*  cbuf = (float*)(ws + (size_t)M_TOT*KDIM*2 + (size_t)NDIM*KDIM*2); // 128 KB
  float*  score= (float*)((char*)cbuf + (size_t)BDIM*NDIM*4);        // NPART x 256 KB partials

  cvt_kernel<<<4096, 256, 0, stream>>>(x, xb, M_TOT*KDIM/8);
  cvt_kernel<<<512, 256, 0, stream>>>(W1w, w1b, NDIM*KDIM/8);
  prep_c_kernel<<<NDIM, 64, 0, stream>>>(W2w, hid, W1b, W2b, cbuf);
  gemm_score_kernel<<<M_TOT/128 * NPART, 256, 0, stream>>>(xb, w1b, cbuf, Vw, score);
  softmax_kernel<<<BDIM, 256, 0, stream>>>(score, out + (size_t)BDIM*UNITS);
  context_kernel<<<dim3(8, BDIM), 256, 0, stream>>>(xb, score, out);
}